// Round 1
// baseline (1965.843 us; speedup 1.0000x reference)
//
#include <hip/hip_runtime.h>

typedef _Float16 f16x8 __attribute__((ext_vector_type(8)));
typedef _Float16 f16x4 __attribute__((ext_vector_type(4)));
typedef float    f32x4 __attribute__((ext_vector_type(4)));

static constexpr int BATCH = 32;
static constexpr int CDIM  = 256;    // C
static constexpr int HW    = 4096;   // h
static constexpr int AW    = 1024;   // A rows (w)
static constexpr int AH    = 4096;   // A cols (h)
static constexpr int BW    = 256;    // B rows (c)
static constexpr int BH    = 512;    // B cols (d)
static constexpr int CHUNK = 4096;   // tie-rank chunk per block

// ---------------- x f32 -> f16 ----------------
__global__ void cvt_f32_f16_kernel(const float* __restrict__ in, _Float16* __restrict__ out, int n4) {
    int i = blockIdx.x * blockDim.x + threadIdx.x;
    int stride = gridDim.x * blockDim.x;
    for (; i < n4; i += stride) {
        float4 v = reinterpret_cast<const float4*>(in)[i];
        f16x4 o = { (_Float16)v.x, (_Float16)v.y, (_Float16)v.z, (_Float16)v.w };
        reinterpret_cast<f16x4*>(out)[i] = o;
    }
}

// ---------------- radix select (exact j-th order statistic of |s|) ----------------
__global__ void hist_hi_kernel(const float* __restrict__ s, int n, unsigned* __restrict__ hist) {
    int i = blockIdx.x * blockDim.x + threadIdx.x;
    int stride = gridDim.x * blockDim.x;
    for (; i < n; i += stride) {
        unsigned b = (__float_as_uint(s[i]) & 0x7fffffffu) >> 16;
        atomicAdd(&hist[b], 1u);
    }
}

__global__ void hist_lo_kernel(const float* __restrict__ s, int n,
                               const unsigned* __restrict__ sel, unsigned* __restrict__ hist2) {
    unsigned hb = sel[0];
    int i = blockIdx.x * blockDim.x + threadIdx.x;
    int stride = gridDim.x * blockDim.x;
    for (; i < n; i += stride) {
        unsigned bits = __float_as_uint(s[i]) & 0x7fffffffu;
        if ((bits >> 16) == hb) atomicAdd(&hist2[bits & 0xffffu], 1u);
    }
}

// 1 block x 1024 threads. Finds bin containing rank (j - *base_less) in hist[65536].
// out2[0] = bin index, out2[1] = *base_less + (# elements in earlier bins)
__global__ void select_bin_kernel(const unsigned* __restrict__ hist,
                                  const unsigned* __restrict__ base_less,
                                  unsigned j, unsigned* __restrict__ out2) {
    __shared__ unsigned partial[1024];
    __shared__ unsigned excl[1024];
    unsigned t = threadIdx.x;
    unsigned sum = 0;
    for (int k = 0; k < 64; ++k) sum += hist[t * 64 + k];
    partial[t] = sum;
    __syncthreads();
    if (t == 0) {
        unsigned c = 0;
        for (int k = 0; k < 1024; ++k) { excl[k] = c; c += partial[k]; }
    }
    __syncthreads();
    unsigned base = *base_less;
    unsigned target = j - base;  // rank within this histogram
    unsigned c = excl[t];
    if (target >= c && target < c + partial[t]) {
        for (int k = 0; k < 64; ++k) {
            unsigned h = hist[t * 64 + k];
            if (target < c + h) { out2[0] = t * 64 + k; out2[1] = base + c; break; }
            c += h;
        }
    }
}

// ---------------- deterministic tie ranking (stable-argsort semantics) ----------------
__global__ void tie_count_kernel(const float* __restrict__ s, int n,
                                 const unsigned* __restrict__ sel, unsigned* __restrict__ tieCnt) {
    unsigned vcut = (sel[0] << 16) | sel[2];
    int start = blockIdx.x * CHUNK;
    int end = min(n, start + CHUNK);
    __shared__ unsigned cnt;
    if (threadIdx.x == 0) cnt = 0;
    __syncthreads();
    unsigned local = 0;
    for (int i = start + (int)threadIdx.x; i < end; i += blockDim.x)
        if ((__float_as_uint(s[i]) & 0x7fffffffu) == vcut) local++;
    if (local) atomicAdd(&cnt, local);
    __syncthreads();
    if (threadIdx.x == 0) tieCnt[blockIdx.x] = cnt;
}

__global__ void tie_scan_kernel(const unsigned* __restrict__ tieCnt, unsigned* __restrict__ tieOff, int nb) {
    if (blockIdx.x == 0 && threadIdx.x == 0) {
        unsigned c = 0;
        for (int i = 0; i < nb; ++i) { tieOff[i] = c; c += tieCnt[i]; }
    }
}

// mask = 1 if |s| > vcut; 0 if < vcut; for ties: keep the ones with LARGEST index
// (stable ascending argsort => ties occupy positions in index order; positions >= j kept).
// drop = j - c_less ties (smallest indices) get 0.
template<bool TR>
__global__ void apply_mask_kernel(const float* __restrict__ s, const float* __restrict__ w,
                                  int n, int rows, int cols,
                                  const unsigned* __restrict__ sel, unsigned j,
                                  const unsigned* __restrict__ tieOff,
                                  _Float16* __restrict__ out) {
    const unsigned vcut = (sel[0] << 16) | sel[2];
    const unsigned drop = j - sel[3];
    int start = blockIdx.x * CHUNK;
    int end = min(n, start + CHUNK);
    __shared__ unsigned segBase;
    __shared__ unsigned wcnt[4];
    if (threadIdx.x == 0) segBase = tieOff[blockIdx.x];
    __syncthreads();
    for (int base = start; base < end; base += (int)blockDim.x) {
        int i = base + (int)threadIdx.x;
        bool valid = i < end;
        unsigned bits = 0;
        if (valid) bits = __float_as_uint(s[i]) & 0x7fffffffu;
        bool tie = valid && (bits == vcut);
        unsigned long long m = __ballot(tie);
        int lane = threadIdx.x & 63;
        int wid  = threadIdx.x >> 6;
        if (lane == 0) wcnt[wid] = (unsigned)__popcll(m);
        unsigned lower = (unsigned)__popcll(m & ((1ull << lane) - 1ull));
        __syncthreads();
        unsigned wbase = 0, tot = 0;
        for (int q = 0; q < 4; ++q) { if (q < wid) wbase += wcnt[q]; tot += wcnt[q]; }
        unsigned myrank = segBase + wbase + lower;
        if (valid) {
            float mask;
            if (bits > vcut)      mask = 1.0f;
            else if (bits < vcut) mask = 0.0f;
            else                  mask = (myrank >= drop) ? 1.0f : 0.0f;
            float v = w[i] * mask;
            int oidx;
            if (TR) { int r = i / cols, c = i - r * cols; oidx = c * rows + r; }
            else    { oidx = i; }
            out[oidx] = (_Float16)v;
        }
        __syncthreads();
        if (threadIdx.x == 0) segBase += tot;
        __syncthreads();
    }
}

// ---------------- batched NT GEMM: out[z][m][n] = sum_k A[z][m][k] * B[z][n][k] ----------------
// A: row-major [M][K] (batch stride aStride elems, 0 = shared)
// B: row-major [N][K] (batch stride bStride elems, 0 = shared)
// 128x128 tile, BK=64, 4 waves (2x2), each wave 64x64 via 4x4 mfma_f32_16x16x32_f16 frags.
// LDS tiles XOR-swizzled (T2-style) to kill ds_read_b128 bank conflicts.
template<bool OUT_F32>
__global__ __launch_bounds__(256) void gemm_nt_kernel(
        const _Float16* __restrict__ A, long aStride,
        const _Float16* __restrict__ B, long bStride,
        void* __restrict__ outP, int M, int N, int K) {
    __shared__ __align__(16) char lds[32768];
    char* As = lds;
    char* Bs = lds + 16384;
    const int t = threadIdx.x;
    const int lane = t & 63;
    const int wave = t >> 6;
    const int wm = (wave >> 1) * 64;
    const int wn = (wave & 1) * 64;
    const int z = blockIdx.z;
    const _Float16* Ab = A + (size_t)z * aStride + (size_t)blockIdx.y * 128 * K;
    const _Float16* Bb = B + (size_t)z * bStride + (size_t)blockIdx.x * 128 * K;

    f32x4 acc[4][4] = {};

    for (int kt = 0; kt < K; kt += 64) {
        __syncthreads();
        #pragma unroll
        for (int i = 0; i < 4; ++i) {
            int c = i * 256 + t;          // 0..1023: 16B chunk id
            int row = c >> 3;             // 0..127
            int kk = c & 7;               // 16B chunk within row
            f16x8 v = *reinterpret_cast<const f16x8*>(Ab + (size_t)row * K + kt + kk * 8);
            int bo = (row * 128 + kk * 16) ^ ((row & 7) << 4);
            *reinterpret_cast<f16x8*>(As + bo) = v;
        }
        #pragma unroll
        for (int i = 0; i < 4; ++i) {
            int c = i * 256 + t;
            int row = c >> 3;
            int kk = c & 7;
            f16x8 v = *reinterpret_cast<const f16x8*>(Bb + (size_t)row * K + kt + kk * 8);
            int bo = (row * 128 + kk * 16) ^ ((row & 7) << 4);
            *reinterpret_cast<f16x8*>(Bs + bo) = v;
        }
        __syncthreads();
        #pragma unroll
        for (int kk = 0; kk < 2; ++kk) {
            f16x8 af[4], bf[4];
            int kByte = kk * 64 + (lane >> 4) * 16;
            #pragma unroll
            for (int mi = 0; mi < 4; ++mi) {
                int row = wm + mi * 16 + (lane & 15);
                int bo = (row * 128 + kByte) ^ ((row & 7) << 4);
                af[mi] = *reinterpret_cast<const f16x8*>(As + bo);
            }
            #pragma unroll
            for (int ni = 0; ni < 4; ++ni) {
                int row = wn + ni * 16 + (lane & 15);
                int bo = (row * 128 + kByte) ^ ((row & 7) << 4);
                bf[ni] = *reinterpret_cast<const f16x8*>(Bs + bo);
            }
            #pragma unroll
            for (int mi = 0; mi < 4; ++mi)
                #pragma unroll
                for (int ni = 0; ni < 4; ++ni)
                    acc[mi][ni] = __builtin_amdgcn_mfma_f32_16x16x32_f16(af[mi], bf[ni], acc[mi][ni], 0, 0, 0);
        }
    }

    // epilogue: D row = (lane>>4)*4 + r, col = lane&15  [verified C/D layout]
    int row0 = blockIdx.y * 128 + wm + ((lane >> 4) << 2);
    int col0 = blockIdx.x * 128 + wn + (lane & 15);
    size_t outBase = (size_t)z * M * N;
    #pragma unroll
    for (int mi = 0; mi < 4; ++mi)
        #pragma unroll
        for (int ni = 0; ni < 4; ++ni)
            #pragma unroll
            for (int r = 0; r < 4; ++r) {
                int gr = row0 + mi * 16 + r;
                int gc = col0 + ni * 16;
                if constexpr (OUT_F32)
                    ((float*)outP)[outBase + (size_t)gr * N + gc] = acc[mi][ni][r];
                else
                    ((_Float16*)outP)[outBase + (size_t)gr * N + gc] = (_Float16)acc[mi][ni][r];
            }
}

// ---------------- launch ----------------
extern "C" void kernel_launch(void* const* d_in, const int* in_sizes, int n_in,
                              void* d_out, int out_size, void* d_ws, size_t ws_size,
                              hipStream_t stream) {
    const float* x     = (const float*)d_in[0];
    const float* A_ref = (const float*)d_in[1];
    const float* B_ref = (const float*)d_in[2];
    const float* sA    = (const float*)d_in[3];
    const float* sB    = (const float*)d_in[4];
    float* out = (float*)d_out;
    char* ws = (char*)d_ws;

    const int nA = AW * AH, jA = nA / 2;
    const int nB = BW * BH, jB = nB / 2;
    const int nx = BATCH * CDIM * HW;
    const int outElems = BATCH * AW * BH;  // 16,777,216 f32

    _Float16* Am    = (_Float16*)(ws + 0);          // [1024][4096] f16
    _Float16* BmT   = (_Float16*)(ws + 8388608);    // [512][256]  f16 (transposed masked B)
    _Float16* temp  = (_Float16*)(ws + 8650752);    // [32][1024][256] f16
    unsigned* hist1 = (unsigned*)(ws + 25427968);
    unsigned* hist2 = (unsigned*)(ws + 25690112);
    unsigned* sel   = (unsigned*)(ws + 25952256);   // [0]=hi_bin [1]=c_less_hi [2]=lo_bin [3]=c_less [4]=zero
    unsigned* tieCnt= (unsigned*)(ws + 25952512);
    unsigned* tieOff= (unsigned*)(ws + 25960704);

    // x (f32) -> f16, overlaid on the d_out "out" region (exactly 67.1MB; GEMM2 overwrites later)
    _Float16* xf16 = (_Float16*)d_out;
    cvt_f32_f16_kernel<<<4096, 256, 0, stream>>>(x, xf16, nx / 4);

    // ---- mask pipeline A ----
    hipMemsetAsync(hist1, 0, 65536 * 4, stream);
    hipMemsetAsync(sel, 0, 32, stream);
    hist_hi_kernel<<<2048, 256, 0, stream>>>(sA, nA, hist1);
    select_bin_kernel<<<1, 1024, 0, stream>>>(hist1, sel + 4, (unsigned)jA, sel + 0);
    hipMemsetAsync(hist2, 0, 65536 * 4, stream);
    hist_lo_kernel<<<2048, 256, 0, stream>>>(sA, nA, sel, hist2);
    select_bin_kernel<<<1, 1024, 0, stream>>>(hist2, sel + 1, (unsigned)jA, sel + 2);
    tie_count_kernel<<<nA / CHUNK, 256, 0, stream>>>(sA, nA, sel, tieCnt);
    tie_scan_kernel<<<1, 1, 0, stream>>>(tieCnt, tieOff, nA / CHUNK);
    apply_mask_kernel<false><<<nA / CHUNK, 256, 0, stream>>>(sA, A_ref, nA, AW, AH, sel, (unsigned)jA, tieOff, Am);

    // ---- mask pipeline B (writes transposed [BH][BW]) ----
    hipMemsetAsync(hist1, 0, 65536 * 4, stream);
    hipMemsetAsync(sel, 0, 32, stream);
    hist_hi_kernel<<<512, 256, 0, stream>>>(sB, nB, hist1);
    select_bin_kernel<<<1, 1024, 0, stream>>>(hist1, sel + 4, (unsigned)jB, sel + 0);
    hipMemsetAsync(hist2, 0, 65536 * 4, stream);
    hist_lo_kernel<<<512, 256, 0, stream>>>(sB, nB, sel, hist2);
    select_bin_kernel<<<1, 1024, 0, stream>>>(hist2, sel + 1, (unsigned)jB, sel + 2);
    tie_count_kernel<<<nB / CHUNK, 256, 0, stream>>>(sB, nB, sel, tieCnt);
    tie_scan_kernel<<<1, 1, 0, stream>>>(tieCnt, tieOff, nB / CHUNK);
    apply_mask_kernel<true><<<nB / CHUNK, 256, 0, stream>>>(sB, B_ref, nB, BW, BH, sel, (unsigned)jB, tieOff, BmT);

    // ---- GEMM1: temp[b][w][c] = sum_h Am[w][h] * x[b][c][h] ----
    gemm_nt_kernel<false><<<dim3(CDIM / 128, AW / 128, BATCH), 256, 0, stream>>>(
        Am, 0, xf16, (long)CDIM * HW, temp, AW, CDIM, HW);

    // ---- GEMM2: out[b][w][d] = sum_c temp[b][w][c] * BmT[d][c] ----
    gemm_nt_kernel<true><<<dim3(BH / 128, AW / 128, BATCH), 256, 0, stream>>>(
        temp, (long)AW * CDIM, BmT, 0, out, AW, BH, CDIM);

    // ---- pass-through outputs ----
    hipMemcpyAsync(out + outElems, A_ref, (size_t)nA * 4, hipMemcpyDeviceToDevice, stream);
    hipMemcpyAsync(out + outElems + nA, B_ref, (size_t)nB * 4, hipMemcpyDeviceToDevice, stream);
}

// Round 2
// 313.721 us; speedup vs baseline: 6.2662x; 6.2662x over previous
//
#include <hip/hip_runtime.h>

typedef _Float16 f16x8 __attribute__((ext_vector_type(8)));
typedef _Float16 f16x4 __attribute__((ext_vector_type(4)));
typedef float    f32x4 __attribute__((ext_vector_type(4)));

static constexpr int BATCH = 32;
static constexpr int CDIM  = 256;    // C
static constexpr int HW    = 4096;   // h
static constexpr int AW    = 1024;   // A rows (w)
static constexpr int AH    = 4096;   // A cols (h)
static constexpr int BW    = 256;    // B rows (c)
static constexpr int BH    = 512;    // B cols (d)
static constexpr int CHUNK = 4096;   // tie-rank chunk per block

// ---------------- x f32 -> f16 ----------------
__global__ void cvt_f32_f16_kernel(const float* __restrict__ in, _Float16* __restrict__ out, int n4) {
    int i = blockIdx.x * blockDim.x + threadIdx.x;
    int stride = gridDim.x * blockDim.x;
    for (; i < n4; i += stride) {
        float4 v = reinterpret_cast<const float4*>(in)[i];
        f16x4 o = { (_Float16)v.x, (_Float16)v.y, (_Float16)v.z, (_Float16)v.w };
        reinterpret_cast<f16x4*>(out)[i] = o;
    }
}

// ---------------- radix select: 3 passes (12+12+7 bits) over 31-bit |s| key ----------------
// Per-wave LDS-private histograms -> near-zero atomic contention.
// sel layout: [0]=bin1 [1]=cless1 [2]=bin2 [3]=cless2 [4]=bin3 [5]=cless3 [6]=0
// MODE 0: all elements, bin = key>>19          (BINS=4096)
// MODE 1: key>>19 == sel[0], bin = (key>>7)&4095   (BINS=4096)
// MODE 2: key>>7 == (sel[0]<<12)|sel[2], bin = key&127  (BINS=128)
template<int BINS, int SHIFT, int MODE>
__global__ void hist_pass_kernel(const float* __restrict__ s, int n,
                                 const unsigned* __restrict__ sel,
                                 unsigned* __restrict__ hist) {
    __shared__ unsigned lh[4][BINS];
    const int t = threadIdx.x;
    const int wave = t >> 6;
    for (int i = t; i < 4 * BINS; i += 256) ((unsigned*)lh)[i] = 0;
    __syncthreads();
    unsigned mv = 0;
    if (MODE == 1) mv = sel[0];
    if (MODE == 2) mv = (sel[0] << 12) | sel[2];
    int i = blockIdx.x * blockDim.x + threadIdx.x;
    int stride = gridDim.x * blockDim.x;
    for (; i < n; i += stride) {
        unsigned key = __float_as_uint(s[i]) & 0x7fffffffu;
        bool ok = (MODE == 0) || (MODE == 1 && (key >> 19) == mv) || (MODE == 2 && (key >> 7) == mv);
        if (ok) atomicAdd(&lh[wave][(key >> SHIFT) & (BINS - 1)], 1u);
    }
    __syncthreads();
    for (int b = t; b < BINS; b += 256) {
        unsigned v = lh[0][b] + lh[1][b] + lh[2][b] + lh[3][b];
        if (v) atomicAdd(&hist[b], v);
    }
}

// 1 block x 256 threads. Finds bin containing rank (j - *basePtr) in hist[BINS].
// sel[binIdx] = bin, sel[baseIdx] = *basePtr + count of earlier bins.
template<int BINS>
__global__ void select_bin_kernel(const unsigned* __restrict__ hist,
                                  const unsigned* __restrict__ basePtr,
                                  unsigned j, unsigned* __restrict__ sel,
                                  int binIdx, int baseIdx) {
    constexpr int PER = (BINS + 255) / 256;
    __shared__ unsigned partial[256];
    __shared__ unsigned excl[256];
    int t = threadIdx.x;
    unsigned sum = 0;
    #pragma unroll
    for (int k = 0; k < PER; ++k) { int b = t * PER + k; if (b < BINS) sum += hist[b]; }
    partial[t] = sum;
    __syncthreads();
    if (t == 0) { unsigned c = 0; for (int k = 0; k < 256; ++k) { excl[k] = c; c += partial[k]; } }
    __syncthreads();
    unsigned base = *basePtr;
    unsigned target = j - base;
    unsigned c = excl[t];
    if (target >= c && target < c + partial[t]) {
        #pragma unroll
        for (int k = 0; k < PER; ++k) {
            int b = t * PER + k;
            unsigned h = (b < BINS) ? hist[b] : 0;
            if (target < c + h) { sel[binIdx] = (unsigned)b; sel[baseIdx] = base + c; break; }
            c += h;
        }
    }
}

// ---------------- deterministic tie ranking (stable-argsort semantics) ----------------
__global__ void tie_count_kernel(const float* __restrict__ s, int n,
                                 const unsigned* __restrict__ sel, unsigned* __restrict__ tieCnt) {
    unsigned vcut = (sel[0] << 19) | (sel[2] << 7) | sel[4];
    int start = blockIdx.x * CHUNK;
    int end = min(n, start + CHUNK);
    __shared__ unsigned cnt;
    if (threadIdx.x == 0) cnt = 0;
    __syncthreads();
    unsigned local = 0;
    for (int i = start + (int)threadIdx.x; i < end; i += blockDim.x)
        if ((__float_as_uint(s[i]) & 0x7fffffffu) == vcut) local++;
    if (local) atomicAdd(&cnt, local);
    __syncthreads();
    if (threadIdx.x == 0) tieCnt[blockIdx.x] = cnt;
}

// parallel exclusive scan of tieCnt[nb] (nb <= 1024), 1 block x 1024 threads
__global__ void tie_scan_kernel(const unsigned* __restrict__ tieCnt, unsigned* __restrict__ tieOff, int nb) {
    __shared__ unsigned buf[1024];
    int t = threadIdx.x;
    unsigned own = (t < nb) ? tieCnt[t] : 0;
    buf[t] = own;
    __syncthreads();
    for (int off = 1; off < 1024; off <<= 1) {
        unsigned u = (t >= off) ? buf[t - off] : 0;
        __syncthreads();
        buf[t] += u;
        __syncthreads();
    }
    if (t < nb) tieOff[t] = buf[t] - own;
}

// mask = 1 if |s| > vcut; 0 if < vcut; ties: keep largest indices (stable ascending argsort).
template<bool TR>
__global__ void apply_mask_kernel(const float* __restrict__ s, const float* __restrict__ w,
                                  int n, int rows, int cols,
                                  const unsigned* __restrict__ sel, unsigned j,
                                  const unsigned* __restrict__ tieOff,
                                  _Float16* __restrict__ out) {
    const unsigned vcut = (sel[0] << 19) | (sel[2] << 7) | sel[4];
    const unsigned drop = j - sel[5];
    int start = blockIdx.x * CHUNK;
    int end = min(n, start + CHUNK);
    __shared__ unsigned segBase;
    __shared__ unsigned wcnt[4];
    if (threadIdx.x == 0) segBase = tieOff[blockIdx.x];
    __syncthreads();
    for (int base = start; base < end; base += (int)blockDim.x) {
        int i = base + (int)threadIdx.x;
        bool valid = i < end;
        unsigned bits = 0;
        if (valid) bits = __float_as_uint(s[i]) & 0x7fffffffu;
        bool tie = valid && (bits == vcut);
        unsigned long long m = __ballot(tie);
        int lane = threadIdx.x & 63;
        int wid  = threadIdx.x >> 6;
        if (lane == 0) wcnt[wid] = (unsigned)__popcll(m);
        unsigned lower = (unsigned)__popcll(m & ((1ull << lane) - 1ull));
        __syncthreads();
        unsigned wbase = 0, tot = 0;
        for (int q = 0; q < 4; ++q) { if (q < wid) wbase += wcnt[q]; tot += wcnt[q]; }
        unsigned myrank = segBase + wbase + lower;
        if (valid) {
            float mask;
            if (bits > vcut)      mask = 1.0f;
            else if (bits < vcut) mask = 0.0f;
            else                  mask = (myrank >= drop) ? 1.0f : 0.0f;
            float v = w[i] * mask;
            int oidx;
            if (TR) { int r = i / cols, c = i - r * cols; oidx = c * rows + r; }
            else    { oidx = i; }
            out[oidx] = (_Float16)v;
        }
        __syncthreads();
        if (threadIdx.x == 0) segBase += tot;
        __syncthreads();
    }
}

// ---------------- batched NT GEMM: out[z][m][n] = sum_k A[z][m][k] * B[z][n][k] ----------------
// 128x128 tile, BK=64, 4 waves (2x2), each wave 64x64 via 4x4 mfma_f32_16x16x32_f16 frags.
// LDS tiles XOR-swizzled (T2-style) to kill ds_read_b128 bank conflicts.
template<bool OUT_F32>
__global__ __launch_bounds__(256) void gemm_nt_kernel(
        const _Float16* __restrict__ A, long aStride,
        const _Float16* __restrict__ B, long bStride,
        void* __restrict__ outP, int M, int N, int K) {
    __shared__ __align__(16) char lds[32768];
    char* As = lds;
    char* Bs = lds + 16384;
    const int t = threadIdx.x;
    const int lane = t & 63;
    const int wave = t >> 6;
    const int wm = (wave >> 1) * 64;
    const int wn = (wave & 1) * 64;
    const int z = blockIdx.z;
    const _Float16* Ab = A + (size_t)z * aStride + (size_t)blockIdx.y * 128 * K;
    const _Float16* Bb = B + (size_t)z * bStride + (size_t)blockIdx.x * 128 * K;

    f32x4 acc[4][4] = {};

    for (int kt = 0; kt < K; kt += 64) {
        __syncthreads();
        #pragma unroll
        for (int i = 0; i < 4; ++i) {
            int c = i * 256 + t;          // 0..1023: 16B chunk id
            int row = c >> 3;             // 0..127
            int kk = c & 7;               // 16B chunk within row
            f16x8 v = *reinterpret_cast<const f16x8*>(Ab + (size_t)row * K + kt + kk * 8);
            int bo = (row * 128 + kk * 16) ^ ((row & 7) << 4);
            *reinterpret_cast<f16x8*>(As + bo) = v;
        }
        #pragma unroll
        for (int i = 0; i < 4; ++i) {
            int c = i * 256 + t;
            int row = c >> 3;
            int kk = c & 7;
            f16x8 v = *reinterpret_cast<const f16x8*>(Bb + (size_t)row * K + kt + kk * 8);
            int bo = (row * 128 + kk * 16) ^ ((row & 7) << 4);
            *reinterpret_cast<f16x8*>(Bs + bo) = v;
        }
        __syncthreads();
        #pragma unroll
        for (int kk = 0; kk < 2; ++kk) {
            f16x8 af[4], bf[4];
            int kByte = kk * 64 + (lane >> 4) * 16;
            #pragma unroll
            for (int mi = 0; mi < 4; ++mi) {
                int row = wm + mi * 16 + (lane & 15);
                int bo = (row * 128 + kByte) ^ ((row & 7) << 4);
                af[mi] = *reinterpret_cast<const f16x8*>(As + bo);
            }
            #pragma unroll
            for (int ni = 0; ni < 4; ++ni) {
                int row = wn + ni * 16 + (lane & 15);
                int bo = (row * 128 + kByte) ^ ((row & 7) << 4);
                bf[ni] = *reinterpret_cast<const f16x8*>(Bs + bo);
            }
            #pragma unroll
            for (int mi = 0; mi < 4; ++mi)
                #pragma unroll
                for (int ni = 0; ni < 4; ++ni)
                    acc[mi][ni] = __builtin_amdgcn_mfma_f32_16x16x32_f16(af[mi], bf[ni], acc[mi][ni], 0, 0, 0);
        }
    }

    // epilogue: D row = (lane>>4)*4 + r, col = lane&15
    int row0 = blockIdx.y * 128 + wm + ((lane >> 4) << 2);
    int col0 = blockIdx.x * 128 + wn + (lane & 15);
    size_t outBase = (size_t)z * M * N;
    #pragma unroll
    for (int mi = 0; mi < 4; ++mi)
        #pragma unroll
        for (int ni = 0; ni < 4; ++ni)
            #pragma unroll
            for (int r = 0; r < 4; ++r) {
                int gr = row0 + mi * 16 + r;
                int gc = col0 + ni * 16;
                if constexpr (OUT_F32)
                    ((float*)outP)[outBase + (size_t)gr * N + gc] = acc[mi][ni][r];
                else
                    ((_Float16*)outP)[outBase + (size_t)gr * N + gc] = (_Float16)acc[mi][ni][r];
            }
}

// ---------------- launch ----------------
extern "C" void kernel_launch(void* const* d_in, const int* in_sizes, int n_in,
                              void* d_out, int out_size, void* d_ws, size_t ws_size,
                              hipStream_t stream) {
    const float* x     = (const float*)d_in[0];
    const float* A_ref = (const float*)d_in[1];
    const float* B_ref = (const float*)d_in[2];
    const float* sA    = (const float*)d_in[3];
    const float* sB    = (const float*)d_in[4];
    float* out = (float*)d_out;
    char* ws = (char*)d_ws;

    const int nA = AW * AH, jA = nA / 2;
    const int nB = BW * BH, jB = nB / 2;
    const int nx = BATCH * CDIM * HW;
    const int outElems = BATCH * AW * BH;  // 16,777,216 f32

    _Float16* Am    = (_Float16*)(ws + 0);          // [1024][4096] f16
    _Float16* BmT   = (_Float16*)(ws + 8388608);    // [512][256]  f16 (transposed masked B)
    _Float16* temp  = (_Float16*)(ws + 8650752);    // [32][1024][256] f16
    unsigned* hist1 = (unsigned*)(ws + 25427968);   // 4096 bins
    unsigned* hist2 = (unsigned*)(ws + 25444352);   // 4096 bins
    unsigned* hist3 = (unsigned*)(ws + 25460736);   // 128 bins
    unsigned* sel   = (unsigned*)(ws + 25461248);   // 7 entries + zero slot
    unsigned* tieCnt= (unsigned*)(ws + 25461376);
    unsigned* tieOff= (unsigned*)(ws + 25465472);

    // x (f32) -> f16, overlaid on the d_out "out" region (GEMM2 overwrites later)
    _Float16* xf16 = (_Float16*)d_out;
    cvt_f32_f16_kernel<<<4096, 256, 0, stream>>>(x, xf16, nx / 4);

    // ---- mask pipeline A ----
    hipMemsetAsync(hist1, 0, 4096 * 4, stream);
    hipMemsetAsync(hist2, 0, 4096 * 4, stream);
    hipMemsetAsync(hist3, 0, 128 * 4, stream);
    hipMemsetAsync(sel, 0, 32, stream);
    hist_pass_kernel<4096, 19, 0><<<256, 256, 0, stream>>>(sA, nA, sel, hist1);
    select_bin_kernel<4096><<<1, 256, 0, stream>>>(hist1, sel + 6, (unsigned)jA, sel, 0, 1);
    hist_pass_kernel<4096, 7, 1><<<256, 256, 0, stream>>>(sA, nA, sel, hist2);
    select_bin_kernel<4096><<<1, 256, 0, stream>>>(hist2, sel + 1, (unsigned)jA, sel, 2, 3);
    hist_pass_kernel<128, 0, 2><<<256, 256, 0, stream>>>(sA, nA, sel, hist3);
    select_bin_kernel<128><<<1, 256, 0, stream>>>(hist3, sel + 3, (unsigned)jA, sel, 4, 5);
    tie_count_kernel<<<nA / CHUNK, 256, 0, stream>>>(sA, nA, sel, tieCnt);
    tie_scan_kernel<<<1, 1024, 0, stream>>>(tieCnt, tieOff, nA / CHUNK);
    apply_mask_kernel<false><<<nA / CHUNK, 256, 0, stream>>>(sA, A_ref, nA, AW, AH, sel, (unsigned)jA, tieOff, Am);

    // ---- mask pipeline B (writes transposed [BH][BW]) ----
    hipMemsetAsync(hist1, 0, 4096 * 4, stream);
    hipMemsetAsync(hist2, 0, 4096 * 4, stream);
    hipMemsetAsync(hist3, 0, 128 * 4, stream);
    hipMemsetAsync(sel, 0, 32, stream);
    hist_pass_kernel<4096, 19, 0><<<64, 256, 0, stream>>>(sB, nB, sel, hist1);
    select_bin_kernel<4096><<<1, 256, 0, stream>>>(hist1, sel + 6, (unsigned)jB, sel, 0, 1);
    hist_pass_kernel<4096, 7, 1><<<64, 256, 0, stream>>>(sB, nB, sel, hist2);
    select_bin_kernel<4096><<<1, 256, 0, stream>>>(hist2, sel + 1, (unsigned)jB, sel, 2, 3);
    hist_pass_kernel<128, 0, 2><<<64, 256, 0, stream>>>(sB, nB, sel, hist3);
    select_bin_kernel<128><<<1, 256, 0, stream>>>(hist3, sel + 3, (unsigned)jB, sel, 4, 5);
    tie_count_kernel<<<nB / CHUNK, 256, 0, stream>>>(sB, nB, sel, tieCnt);
    tie_scan_kernel<<<1, 1024, 0, stream>>>(tieCnt, tieOff, nB / CHUNK);
    apply_mask_kernel<true><<<nB / CHUNK, 256, 0, stream>>>(sB, B_ref, nB, BW, BH, sel, (unsigned)jB, tieOff, BmT);

    // ---- GEMM1: temp[b][w][c] = sum_h Am[w][h] * x[b][c][h] ----
    gemm_nt_kernel<false><<<dim3(CDIM / 128, AW / 128, BATCH), 256, 0, stream>>>(
        Am, 0, xf16, (long)CDIM * HW, temp, AW, CDIM, HW);

    // ---- GEMM2: out[b][w][d] = sum_c temp[b][w][c] * BmT[d][c] ----
    gemm_nt_kernel<true><<<dim3(BH / 128, AW / 128, BATCH), 256, 0, stream>>>(
        temp, (long)AW * CDIM, BmT, 0, out, AW, BH, CDIM);

    // ---- pass-through outputs ----
    hipMemcpyAsync(out + outElems, A_ref, (size_t)nA * 4, hipMemcpyDeviceToDevice, stream);
    hipMemcpyAsync(out + outElems + nA, B_ref, (size_t)nB * 4, hipMemcpyDeviceToDevice, stream);
}

// Round 3
// 310.972 us; speedup vs baseline: 6.3216x; 1.0088x over previous
//
#include <hip/hip_runtime.h>

typedef _Float16 f16x8 __attribute__((ext_vector_type(8)));
typedef float    f32x4 __attribute__((ext_vector_type(4)));

static constexpr int BATCH = 32;
static constexpr int CDIM  = 256;    // C
static constexpr int HW    = 4096;   // h (= A_H = K of GEMM1)
static constexpr int AW    = 1024;   // A rows (w)
static constexpr int AH    = 4096;   // A cols (h)
static constexpr int BW    = 256;    // B rows (c)
static constexpr int BH    = 512;    // B cols (d)
static constexpr int CHUNK = 4096;   // tie-rank chunk per block

__device__ __forceinline__ void gload16(const void* g, void* l) {
    __builtin_amdgcn_global_load_lds((const __attribute__((address_space(1))) void*)g,
                                     (__attribute__((address_space(3))) void*)l, 16, 0, 0);
}

// ---------------- radix select: 3 passes (12+12+7 bits) over 31-bit |s| key ----------------
// Per-wave LDS-private histograms -> near-zero atomic contention.
// sel layout: [0]=bin1 [1]=cless1 [2]=bin2 [3]=cless2 [4]=bin3 [5]=cless3 [6]=0
template<int BINS, int SHIFT, int MODE>
__global__ void hist_pass_kernel(const float* __restrict__ s, int n,
                                 const unsigned* __restrict__ sel,
                                 unsigned* __restrict__ hist) {
    __shared__ unsigned lh[4][BINS];
    const int t = threadIdx.x;
    const int wave = t >> 6;
    for (int i = t; i < 4 * BINS; i += 256) ((unsigned*)lh)[i] = 0;
    __syncthreads();
    unsigned mv = 0;
    if (MODE == 1) mv = sel[0];
    if (MODE == 2) mv = (sel[0] << 12) | sel[2];
    int i = blockIdx.x * blockDim.x + threadIdx.x;
    int stride = gridDim.x * blockDim.x;
    for (; i < n; i += stride) {
        unsigned key = __float_as_uint(s[i]) & 0x7fffffffu;
        bool ok = (MODE == 0) || (MODE == 1 && (key >> 19) == mv) || (MODE == 2 && (key >> 7) == mv);
        if (ok) atomicAdd(&lh[wave][(key >> SHIFT) & (BINS - 1)], 1u);
    }
    __syncthreads();
    for (int b = t; b < BINS; b += 256) {
        unsigned v = lh[0][b] + lh[1][b] + lh[2][b] + lh[3][b];
        if (v) atomicAdd(&hist[b], v);
    }
}

template<int BINS>
__global__ void select_bin_kernel(const unsigned* __restrict__ hist,
                                  const unsigned* __restrict__ basePtr,
                                  unsigned j, unsigned* __restrict__ sel,
                                  int binIdx, int baseIdx) {
    constexpr int PER = (BINS + 255) / 256;
    __shared__ unsigned partial[256];
    __shared__ unsigned excl[256];
    int t = threadIdx.x;
    unsigned sum = 0;
    #pragma unroll
    for (int k = 0; k < PER; ++k) { int b = t * PER + k; if (b < BINS) sum += hist[b]; }
    partial[t] = sum;
    __syncthreads();
    if (t == 0) { unsigned c = 0; for (int k = 0; k < 256; ++k) { excl[k] = c; c += partial[k]; } }
    __syncthreads();
    unsigned base = *basePtr;
    unsigned target = j - base;
    unsigned c = excl[t];
    if (target >= c && target < c + partial[t]) {
        #pragma unroll
        for (int k = 0; k < PER; ++k) {
            int b = t * PER + k;
            unsigned h = (b < BINS) ? hist[b] : 0;
            if (target < c + h) { sel[binIdx] = (unsigned)b; sel[baseIdx] = base + c; break; }
            c += h;
        }
    }
}

// ---------------- deterministic tie ranking (stable-argsort semantics) ----------------
__global__ void tie_count_kernel(const float* __restrict__ s, int n,
                                 const unsigned* __restrict__ sel, unsigned* __restrict__ tieCnt) {
    unsigned vcut = (sel[0] << 19) | (sel[2] << 7) | sel[4];
    int start = blockIdx.x * CHUNK;
    int end = min(n, start + CHUNK);
    __shared__ unsigned cnt;
    if (threadIdx.x == 0) cnt = 0;
    __syncthreads();
    unsigned local = 0;
    for (int i = start + (int)threadIdx.x; i < end; i += blockDim.x)
        if ((__float_as_uint(s[i]) & 0x7fffffffu) == vcut) local++;
    if (local) atomicAdd(&cnt, local);
    __syncthreads();
    if (threadIdx.x == 0) tieCnt[blockIdx.x] = cnt;
}

__global__ void tie_scan_kernel(const unsigned* __restrict__ tieCnt, unsigned* __restrict__ tieOff, int nb) {
    __shared__ unsigned buf[1024];
    int t = threadIdx.x;
    unsigned own = (t < nb) ? tieCnt[t] : 0;
    buf[t] = own;
    __syncthreads();
    for (int off = 1; off < 1024; off <<= 1) {
        unsigned u = (t >= off) ? buf[t - off] : 0;
        __syncthreads();
        buf[t] += u;
        __syncthreads();
    }
    if (t < nb) tieOff[t] = buf[t] - own;
}

// mask = 1 if |s| > vcut; 0 if < vcut; ties: keep largest indices (stable ascending argsort).
// Also writes the f32 pass-through copy of w (fused, saves a separate memcpy pass).
template<bool TR>
__global__ void apply_mask_kernel(const float* __restrict__ s, const float* __restrict__ w,
                                  int n, int rows, int cols,
                                  const unsigned* __restrict__ sel, unsigned j,
                                  const unsigned* __restrict__ tieOff,
                                  _Float16* __restrict__ out, float* __restrict__ wcopy) {
    const unsigned vcut = (sel[0] << 19) | (sel[2] << 7) | sel[4];
    const unsigned drop = j - sel[5];
    int start = blockIdx.x * CHUNK;
    int end = min(n, start + CHUNK);
    __shared__ unsigned segBase;
    __shared__ unsigned wcnt[4];
    if (threadIdx.x == 0) segBase = tieOff[blockIdx.x];
    __syncthreads();
    for (int base = start; base < end; base += (int)blockDim.x) {
        int i = base + (int)threadIdx.x;
        bool valid = i < end;
        unsigned bits = 0;
        if (valid) bits = __float_as_uint(s[i]) & 0x7fffffffu;
        bool tie = valid && (bits == vcut);
        unsigned long long m = __ballot(tie);
        int lane = threadIdx.x & 63;
        int wid  = threadIdx.x >> 6;
        if (lane == 0) wcnt[wid] = (unsigned)__popcll(m);
        unsigned lower = (unsigned)__popcll(m & ((1ull << lane) - 1ull));
        __syncthreads();
        unsigned wbase = 0, tot = 0;
        for (int q = 0; q < 4; ++q) { if (q < wid) wbase += wcnt[q]; tot += wcnt[q]; }
        unsigned myrank = segBase + wbase + lower;
        if (valid) {
            float wv = w[i];
            float mask;
            if (bits > vcut)      mask = 1.0f;
            else if (bits < vcut) mask = 0.0f;
            else                  mask = (myrank >= drop) ? 1.0f : 0.0f;
            float v = wv * mask;
            int oidx;
            if (TR) { int r = i / cols, c = i - r * cols; oidx = c * rows + r; }
            else    { oidx = i; }
            out[oidx] = (_Float16)v;
            wcopy[i] = wv;
        }
        __syncthreads();
        if (threadIdx.x == 0) segBase += tot;
        __syncthreads();
    }
}

// ---------------- GEMM1 (fused x conversion): temp[z][w][c] = sum_h Am[w][h] * x[z][c][h] ----
// A (f16) staged via global_load_lds w/ pre-swizzled source; x (f32) reg-staged + cvt + swizzled ds_write.
// 128x128 tile, BK=64, 4 waves (2x2), 4x4 mfma_f32_16x16x32_f16 per wave.
__global__ __launch_bounds__(256) void gemm1_kernel(
        const _Float16* __restrict__ Am,   // [1024][4096]
        const float* __restrict__ x,       // [32][256][4096]
        _Float16* __restrict__ temp) {     // [32][1024][256]
    __shared__ __align__(16) char lds[32768];
    char* As = lds;
    char* Xs = lds + 16384;
    const int t = threadIdx.x;
    const int lane = t & 63;
    const int wave = t >> 6;
    const int wm = (wave >> 1) * 64;
    const int wn = (wave & 1) * 64;
    const int z = blockIdx.z;

    const int r0 = t >> 3;              // staging row base (0..31), + i*32
    const int kk = t & 7;               // 16B chunk within 128B k-row
    const int kkSwz = kk ^ (r0 & 7);    // inverse-swizzle on source (XOR involution)

    const _Float16* aSrc = Am + (size_t)blockIdx.y * 128 * HW + (size_t)r0 * HW + kkSwz * 8;
    const float*    xSrc = x + ((size_t)z * CDIM + blockIdx.x * 128 + r0) * HW + kk * 8;
    const int xDst = r0 * 128 + kkSwz * 16;   // swizzled LDS byte offset (row-part added per i)

    f32x4 acc[4][4] = {};

    for (int kt = 0; kt < HW; kt += 64) {
        __syncthreads();
        #pragma unroll
        for (int i = 0; i < 4; ++i)
            gload16(aSrc + kt + i * (32 * HW), As + i * 4096 + t * 16);
        #pragma unroll
        for (int i = 0; i < 4; ++i) {
            const float4* p = (const float4*)(xSrc + kt + i * (32 * HW));
            float4 v0 = p[0], v1 = p[1];
            f16x8 h = { (_Float16)v0.x, (_Float16)v0.y, (_Float16)v0.z, (_Float16)v0.w,
                        (_Float16)v1.x, (_Float16)v1.y, (_Float16)v1.z, (_Float16)v1.w };
            *(f16x8*)(Xs + i * 4096 + xDst) = h;
        }
        __syncthreads();
        #pragma unroll
        for (int k2 = 0; k2 < 2; ++k2) {
            f16x8 af[4], bf[4];
            int kByte = k2 * 64 + (lane >> 4) * 16;
            #pragma unroll
            for (int mi = 0; mi < 4; ++mi) {
                int row = wm + mi * 16 + (lane & 15);
                af[mi] = *(const f16x8*)(As + ((row * 128 + kByte) ^ ((row & 7) << 4)));
            }
            #pragma unroll
            for (int ni = 0; ni < 4; ++ni) {
                int row = wn + ni * 16 + (lane & 15);
                bf[ni] = *(const f16x8*)(Xs + ((row * 128 + kByte) ^ ((row & 7) << 4)));
            }
            #pragma unroll
            for (int mi = 0; mi < 4; ++mi)
                #pragma unroll
                for (int ni = 0; ni < 4; ++ni)
                    acc[mi][ni] = __builtin_amdgcn_mfma_f32_16x16x32_f16(af[mi], bf[ni], acc[mi][ni], 0, 0, 0);
        }
    }

    int row0 = blockIdx.y * 128 + wm + ((lane >> 4) << 2);
    int col0 = blockIdx.x * 128 + wn + (lane & 15);
    size_t outBase = (size_t)z * AW * CDIM;
    #pragma unroll
    for (int mi = 0; mi < 4; ++mi)
        #pragma unroll
        for (int ni = 0; ni < 4; ++ni)
            #pragma unroll
            for (int r = 0; r < 4; ++r)
                temp[outBase + (size_t)(row0 + mi * 16 + r) * CDIM + col0 + ni * 16] = (_Float16)acc[mi][ni][r];
}

// ---------------- generic batched NT GEMM, both f16 operands via global_load_lds ----------------
template<bool OUT_F32>
__global__ __launch_bounds__(256) void gemm_nt_lds_kernel(
        const _Float16* __restrict__ A, long aStride,
        const _Float16* __restrict__ B, long bStride,
        void* __restrict__ outP, int M, int N, int K) {
    __shared__ __align__(16) char lds[32768];
    char* As = lds;
    char* Bs = lds + 16384;
    const int t = threadIdx.x;
    const int lane = t & 63;
    const int wave = t >> 6;
    const int wm = (wave >> 1) * 64;
    const int wn = (wave & 1) * 64;
    const int z = blockIdx.z;

    const int r0 = t >> 3;
    const int kk = t & 7;
    const int kkSwz = kk ^ (r0 & 7);

    const _Float16* aSrc = A + (size_t)z * aStride + ((size_t)blockIdx.y * 128 + r0) * K + kkSwz * 8;
    const _Float16* bSrc = B + (size_t)z * bStride + ((size_t)blockIdx.x * 128 + r0) * K + kkSwz * 8;

    f32x4 acc[4][4] = {};

    for (int kt = 0; kt < K; kt += 64) {
        __syncthreads();
        #pragma unroll
        for (int i = 0; i < 4; ++i)
            gload16(aSrc + kt + (size_t)i * 32 * K, As + i * 4096 + t * 16);
        #pragma unroll
        for (int i = 0; i < 4; ++i)
            gload16(bSrc + kt + (size_t)i * 32 * K, Bs + i * 4096 + t * 16);
        __syncthreads();
        #pragma unroll
        for (int k2 = 0; k2 < 2; ++k2) {
            f16x8 af[4], bf[4];
            int kByte = k2 * 64 + (lane >> 4) * 16;
            #pragma unroll
            for (int mi = 0; mi < 4; ++mi) {
                int row = wm + mi * 16 + (lane & 15);
                af[mi] = *(const f16x8*)(As + ((row * 128 + kByte) ^ ((row & 7) << 4)));
            }
            #pragma unroll
            for (int ni = 0; ni < 4; ++ni) {
                int row = wn + ni * 16 + (lane & 15);
                bf[ni] = *(const f16x8*)(Bs + ((row * 128 + kByte) ^ ((row & 7) << 4)));
            }
            #pragma unroll
            for (int mi = 0; mi < 4; ++mi)
                #pragma unroll
                for (int ni = 0; ni < 4; ++ni)
                    acc[mi][ni] = __builtin_amdgcn_mfma_f32_16x16x32_f16(af[mi], bf[ni], acc[mi][ni], 0, 0, 0);
        }
    }

    int row0 = blockIdx.y * 128 + wm + ((lane >> 4) << 2);
    int col0 = blockIdx.x * 128 + wn + (lane & 15);
    size_t outBase = (size_t)z * M * N;
    #pragma unroll
    for (int mi = 0; mi < 4; ++mi)
        #pragma unroll
        for (int ni = 0; ni < 4; ++ni)
            #pragma unroll
            for (int r = 0; r < 4; ++r) {
                int gr = row0 + mi * 16 + r;
                int gc = col0 + ni * 16;
                if constexpr (OUT_F32)
                    ((float*)outP)[outBase + (size_t)gr * N + gc] = acc[mi][ni][r];
                else
                    ((_Float16*)outP)[outBase + (size_t)gr * N + gc] = (_Float16)acc[mi][ni][r];
            }
}

// ---------------- launch ----------------
extern "C" void kernel_launch(void* const* d_in, const int* in_sizes, int n_in,
                              void* d_out, int out_size, void* d_ws, size_t ws_size,
                              hipStream_t stream) {
    const float* x     = (const float*)d_in[0];
    const float* A_ref = (const float*)d_in[1];
    const float* B_ref = (const float*)d_in[2];
    const float* sA    = (const float*)d_in[3];
    const float* sB    = (const float*)d_in[4];
    float* out = (float*)d_out;
    char* ws = (char*)d_ws;

    const int nA = AW * AH, jA = nA / 2;
    const int nB = BW * BH, jB = nB / 2;
    const int outElems = BATCH * AW * BH;  // 16,777,216 f32

    _Float16* Am    = (_Float16*)(ws + 0);          // [1024][4096] f16
    _Float16* BmT   = (_Float16*)(ws + 8388608);    // [512][256]  f16 (transposed masked B)
    _Float16* temp  = (_Float16*)(ws + 8650752);    // [32][1024][256] f16
    unsigned* hist1 = (unsigned*)(ws + 25427968);   // 4096 bins
    unsigned* hist2 = (unsigned*)(ws + 25444352);   // 4096 bins
    unsigned* hist3 = (unsigned*)(ws + 25460736);   // 128 bins
    unsigned* sel   = (unsigned*)(ws + 25461248);   // 7 entries
    unsigned* tieCnt= (unsigned*)(ws + 25461376);
    unsigned* tieOff= (unsigned*)(ws + 25465472);

    // ---- mask pipeline A ----
    hipMemsetAsync(hist1, 0, 4096 * 4, stream);
    hipMemsetAsync(hist2, 0, 4096 * 4, stream);
    hipMemsetAsync(hist3, 0, 128 * 4, stream);
    hipMemsetAsync(sel, 0, 32, stream);
    hist_pass_kernel<4096, 19, 0><<<256, 256, 0, stream>>>(sA, nA, sel, hist1);
    select_bin_kernel<4096><<<1, 256, 0, stream>>>(hist1, sel + 6, (unsigned)jA, sel, 0, 1);
    hist_pass_kernel<4096, 7, 1><<<256, 256, 0, stream>>>(sA, nA, sel, hist2);
    select_bin_kernel<4096><<<1, 256, 0, stream>>>(hist2, sel + 1, (unsigned)jA, sel, 2, 3);
    hist_pass_kernel<128, 0, 2><<<256, 256, 0, stream>>>(sA, nA, sel, hist3);
    select_bin_kernel<128><<<1, 256, 0, stream>>>(hist3, sel + 3, (unsigned)jA, sel, 4, 5);
    tie_count_kernel<<<nA / CHUNK, 256, 0, stream>>>(sA, nA, sel, tieCnt);
    tie_scan_kernel<<<1, 1024, 0, stream>>>(tieCnt, tieOff, nA / CHUNK);
    apply_mask_kernel<false><<<nA / CHUNK, 256, 0, stream>>>(sA, A_ref, nA, AW, AH, sel, (unsigned)jA, tieOff, Am, out + outElems);

    // ---- mask pipeline B (writes transposed [BH][BW]) ----
    hipMemsetAsync(hist1, 0, 4096 * 4, stream);
    hipMemsetAsync(hist2, 0, 4096 * 4, stream);
    hipMemsetAsync(hist3, 0, 128 * 4, stream);
    hipMemsetAsync(sel, 0, 32, stream);
    hist_pass_kernel<4096, 19, 0><<<64, 256, 0, stream>>>(sB, nB, sel, hist1);
    select_bin_kernel<4096><<<1, 256, 0, stream>>>(hist1, sel + 6, (unsigned)jB, sel, 0, 1);
    hist_pass_kernel<4096, 7, 1><<<64, 256, 0, stream>>>(sB, nB, sel, hist2);
    select_bin_kernel<4096><<<1, 256, 0, stream>>>(hist2, sel + 1, (unsigned)jB, sel, 2, 3);
    hist_pass_kernel<128, 0, 2><<<64, 256, 0, stream>>>(sB, nB, sel, hist3);
    select_bin_kernel<128><<<1, 256, 0, stream>>>(hist3, sel + 3, (unsigned)jB, sel, 4, 5);
    tie_count_kernel<<<nB / CHUNK, 256, 0, stream>>>(sB, nB, sel, tieCnt);
    tie_scan_kernel<<<1, 1024, 0, stream>>>(tieCnt, tieOff, nB / CHUNK);
    apply_mask_kernel<true><<<nB / CHUNK, 256, 0, stream>>>(sB, B_ref, nB, BW, BH, sel, (unsigned)jB, tieOff, BmT, out + outElems + nA);

    // ---- GEMM1: temp[b][w][c] = sum_h Am[w][h] * x[b][c][h] (fused f32->f16 on x) ----
    gemm1_kernel<<<dim3(CDIM / 128, AW / 128, BATCH), 256, 0, stream>>>(Am, x, temp);

    // ---- GEMM2: out[b][w][d] = sum_c temp[b][w][c] * BmT[d][c] ----
    gemm_nt_lds_kernel<true><<<dim3(BH / 128, AW / 128, BATCH), 256, 0, stream>>>(
        temp, (long)AW * CDIM, BmT, 0, out, AW, BH, CDIM);
}